// Round 5
// baseline (1542.424 us; speedup 1.0000x reference)
//
#include <hip/hip_runtime.h>
#include <cstdint>
#include <cstddef>

typedef _Float16 half_t;
typedef _Float16 h8 __attribute__((ext_vector_type(8)));
typedef float f4 __attribute__((ext_vector_type(4)));

static constexpr int TOKENS = 16384;   // 64 images * 256 patches
static constexpr int DIM    = 512;
static constexpr int NEXP   = 10;
static constexpr int EHID   = 256;
static constexpr int ECAP   = 4096;    // per (slot,expert) capacity (balanced ~1638)
static constexpr float LSC  = 4096.f;  // lo-part scale (2^12) to avoid fp16 subnormals
static constexpr float LSCI = 1.f / 4096.f;

__device__ __forceinline__ void split_hl(float v, half_t& h, half_t& l) {
  h = (half_t)v;
  l = (half_t)((v - (float)h) * LSC);
}

// ---------------------------------------------------------------- weight prep
// W [K][N] f32 -> W^T hi/lo f16 [N][KP], lo pre-scaled by 2^12. grid(N/32, KP/32, nmat)
__global__ __launch_bounds__(256) void k_wprep(const float* __restrict__ W,
                                               half_t* __restrict__ Ohi,
                                               half_t* __restrict__ Olo,
                                               int K, int N, int KP)
{
  __shared__ float T[32][33];
  const int z = blockIdx.z;
  W   += (size_t)z * K * N;
  Ohi += (size_t)z * N * KP;
  Olo += (size_t)z * N * KP;
  const int t = threadIdx.x;
  const int bn = blockIdx.x * 32, bk = blockIdx.y * 32;
  {
    int nl = t & 31, kq = t >> 5;
#pragma unroll
    for (int i = 0; i < 4; ++i) {
      int kl = kq + i * 8;
      int k = bk + kl;
      T[kl][nl] = (k < K) ? W[(size_t)k * N + bn + nl] : 0.f;
    }
  }
  __syncthreads();
  {
    int kl = t & 31, nq = t >> 5;
#pragma unroll
    for (int i = 0; i < 4; ++i) {
      int nl = nq + i * 8;
      half_t h, l; split_hl(T[kl][nl], h, l);
      size_t o = (size_t)(bn + nl) * KP + bk + kl;
      Ohi[o] = h; Olo[o] = l;
    }
  }
}

// ---------------------------------------------------------------- patchify
// x [64,1,224,224] -> P_hi/P_lo [16384][224] (zero-padded cols 196..223)
__global__ __launch_bounds__(256) void k_patchify(const float* __restrict__ x,
                                                  half_t* __restrict__ Phi,
                                                  half_t* __restrict__ Plo)
{
  int gid = blockIdx.x * 256 + threadIdx.x;
  if (gid >= TOKENS * 224) return;
  int tk = gid / 224, p = gid - tk * 224;
  float v = 0.f;
  if (p < 196) {
    int b = tk >> 8, n = tk & 255;
    int ni = n >> 4, nj = n & 15;
    int pi = p / 14, pj = p - pi * 14;
    v = x[(size_t)b * 50176 + (size_t)(ni * 14 + pi) * 224 + (nj * 14 + pj)];
  }
  half_t h, l; split_hl(v, h, l);
  Phi[gid] = h; Plo[gid] = l;
}

// ---------------------------------------------------------------- MFMA GEMM
// C[M,N] = A[M,K] @ B^T[N,K] (+bias). A,B fp16 hi/lo pairs (lo scaled 2^12).
// BM=128 BN=128 BK=32, 256 thr = 4 waves (2m x 2n), wave tile 64x64 (4x4 frags).
// EPI: 0 = +bias+pos -> HL ; 1 = +bias -> HL ; 2 = +bias -> F32 ; 3 = +bias -> F32+HL
template <int EPI>
__global__ __launch_bounds__(256) void k_mgemm(
    const half_t* __restrict__ Ahi, const half_t* __restrict__ Alo,
    const half_t* __restrict__ Bhi, const half_t* __restrict__ Blo,
    const float* __restrict__ bias, const float* __restrict__ pos,
    float* __restrict__ Cf, half_t* __restrict__ Chi, half_t* __restrict__ Clo,
    int K, int Cld)
{
  __shared__ half_t Ah[128][40], Al[128][40], Bh[128][40], Bl[128][40];
  const int tid = threadIdx.x;
  const int row0 = blockIdx.x * 128;
  const int col0 = blockIdx.y * 128;
  const int lane = tid & 63, wid = tid >> 6;
  const int wm = wid & 1, wn = wid >> 1;
  const int l16 = lane & 15, lq = lane >> 4;
  f4 acc1[4][4], acc2[4][4];
#pragma unroll
  for (int a = 0; a < 4; ++a)
#pragma unroll
    for (int b = 0; b < 4; ++b) {
      acc1[a][b] = {0.f, 0.f, 0.f, 0.f};
      acc2[a][b] = {0.f, 0.f, 0.f, 0.f};
    }
  for (int k0 = 0; k0 < K; k0 += 32) {
    // stage A(128x32) and B(128x32) hi+lo: 2 x 16B per matrix per thread
#pragma unroll
    for (int i = 0; i < 2; ++i) {
      int lin = tid + i * 256;
      int r = lin >> 2, kc = (lin & 3) << 3;
      const size_t ga = (size_t)(row0 + r) * K + k0 + kc;
      *(uint4*)&Ah[r][kc] = *(const uint4*)&Ahi[ga];
      *(uint4*)&Al[r][kc] = *(const uint4*)&Alo[ga];
      const size_t gb = (size_t)(col0 + r) * K + k0 + kc;
      *(uint4*)&Bh[r][kc] = *(const uint4*)&Bhi[gb];
      *(uint4*)&Bl[r][kc] = *(const uint4*)&Blo[gb];
    }
    __syncthreads();
    h8 ah[4], al2[4];
#pragma unroll
    for (int mt = 0; mt < 4; ++mt) {
      int r = wm * 64 + mt * 16 + l16;
      ah[mt]  = *(const h8*)&Ah[r][lq * 8];
      al2[mt] = *(const h8*)&Al[r][lq * 8];
    }
#pragma unroll
    for (int nt = 0; nt < 4; ++nt) {
      int rb = wn * 64 + nt * 16 + l16;
      h8 bh = *(const h8*)&Bh[rb][lq * 8];
      h8 bl = *(const h8*)&Bl[rb][lq * 8];
#pragma unroll
      for (int mt = 0; mt < 4; ++mt) {
        acc1[mt][nt] = __builtin_amdgcn_mfma_f32_16x16x32_f16(ah[mt], bh, acc1[mt][nt], 0, 0, 0);
        acc2[mt][nt] = __builtin_amdgcn_mfma_f32_16x16x32_f16(ah[mt], bl, acc2[mt][nt], 0, 0, 0);
        acc2[mt][nt] = __builtin_amdgcn_mfma_f32_16x16x32_f16(al2[mt], bh, acc2[mt][nt], 0, 0, 0);
      }
    }
    __syncthreads();
  }
#pragma unroll
  for (int mt = 0; mt < 4; ++mt) {
#pragma unroll
    for (int nt = 0; nt < 4; ++nt) {
      const int col = col0 + wn * 64 + nt * 16 + l16;
      const float bv = bias[col];
#pragma unroll
      for (int r = 0; r < 4; ++r) {
        const int row = row0 + wm * 64 + mt * 16 + lq * 4 + r;
        float v = acc1[mt][nt][r] + acc2[mt][nt][r] * LSCI + bv;
        if (EPI == 0) v += pos[(size_t)(row & 255) * 512 + col];
        const size_t ci = (size_t)row * Cld + col;
        if (EPI == 2 || EPI == 3) Cf[ci] = v;
        if (EPI == 0 || EPI == 1 || EPI == 3) {
          half_t h, l; split_hl(v, h, l);
          Chi[ci] = h; Clo[ci] = l;
        }
      }
    }
  }
}

// ---------------------------------------------------------------- attention (fp32)
// Per (patch n, head h): 64x64 attention over the IMAGE axis. qkv row stride 1536.
__global__ __launch_bounds__(256) void k_attn(const float* __restrict__ qkv,
                                              half_t* __restrict__ oHi,
                                              half_t* __restrict__ oLo)
{
  __shared__ float Qs[64][68];
  __shared__ float Ks[64][68];
  __shared__ float Vs[64][68];
  const int n = blockIdx.x;
  const int h = blockIdx.y;
  const int tid = threadIdx.x;
  const int l = tid >> 2, q = tid & 3;
  {
    const float* rowp = qkv + (size_t)(l * 256 + n) * 1536 + h * 64;
#pragma unroll
    for (int i = 0; i < 4; ++i) {
      int c = q * 16 + i * 4;
      *(float4*)&Qs[l][c] = *(const float4*)(rowp + c);
      *(float4*)&Ks[l][c] = *(const float4*)(rowp + 512 + c);
      *(float4*)&Vs[l][c] = *(const float4*)(rowp + 1024 + c);
    }
  }
  __syncthreads();
  float s[16];
#pragma unroll
  for (int j = 0; j < 16; ++j) {
    int m = (j << 2) + q;
    float a = 0.f;
#pragma unroll
    for (int k4 = 0; k4 < 16; ++k4) {
      float4 qa = *(const float4*)&Qs[l][k4 * 4];
      float4 kb = *(const float4*)&Ks[m][k4 * 4];
      a = fmaf(qa.x, kb.x, a); a = fmaf(qa.y, kb.y, a);
      a = fmaf(qa.z, kb.z, a); a = fmaf(qa.w, kb.w, a);
    }
    s[j] = a * 0.125f;
  }
  float mx = s[0];
#pragma unroll
  for (int j = 1; j < 16; ++j) mx = fmaxf(mx, s[j]);
  mx = fmaxf(mx, __shfl_xor(mx, 1));
  mx = fmaxf(mx, __shfl_xor(mx, 2));
  float sum = 0.f;
#pragma unroll
  for (int j = 0; j < 16; ++j) { s[j] = expf(s[j] - mx); sum += s[j]; }
  sum += __shfl_xor(sum, 1);
  sum += __shfl_xor(sum, 2);
  float inv = 1.f / sum;
  __syncthreads();
#pragma unroll
  for (int j = 0; j < 16; ++j) Qs[l][(j << 2) + q] = s[j] * inv;
  __syncthreads();
  float av[16] = {};
  for (int m = 0; m < 64; ++m) {
    float p = Qs[l][m];
#pragma unroll
    for (int i = 0; i < 4; ++i) {
      float4 v4 = *(const float4*)&Vs[m][q * 16 + i * 4];
      av[i * 4 + 0] = fmaf(p, v4.x, av[i * 4 + 0]);
      av[i * 4 + 1] = fmaf(p, v4.y, av[i * 4 + 1]);
      av[i * 4 + 2] = fmaf(p, v4.z, av[i * 4 + 2]);
      av[i * 4 + 3] = fmaf(p, v4.w, av[i * 4 + 3]);
    }
  }
  const size_t base = (size_t)(l * 256 + n) * 512 + h * 64 + q * 16;
  h8 hv0, hv1, lv0, lv1;
#pragma unroll
  for (int i = 0; i < 8; ++i) { half_t hh, ll; split_hl(av[i], hh, ll); hv0[i] = hh; lv0[i] = ll; }
#pragma unroll
  for (int i = 0; i < 8; ++i) { half_t hh, ll; split_hl(av[8 + i], hh, ll); hv1[i] = hh; lv1[i] = ll; }
  *(h8*)&oHi[base] = hv0; *(h8*)&oHi[base + 8] = hv1;
  *(h8*)&oLo[base] = lv0; *(h8*)&oLo[base + 8] = lv1;
}

// ---------------------------------------------------------------- gating
__global__ __launch_bounds__(256) void k_gate(const float* __restrict__ o2,
                                              const float* __restrict__ Wg,
                                              const float* __restrict__ bg,
                                              int2* __restrict__ tok_e,
                                              float2* __restrict__ tok_w)
{
  const int wave = threadIdx.x >> 6;
  const int lane = threadIdx.x & 63;
  const int t = blockIdx.x * 4 + wave;
  const float* xr = o2 + (size_t)t * DIM;
  float acc[NEXP];
#pragma unroll
  for (int e = 0; e < NEXP; ++e) acc[e] = 0.f;
#pragma unroll
  for (int i = 0; i < 8; ++i) {
    int d = i * 64 + lane;
    float xv = xr[d];
    const float* wr = Wg + (size_t)d * NEXP;
#pragma unroll
    for (int e = 0; e < NEXP; ++e) acc[e] = fmaf(xv, wr[e], acc[e]);
  }
#pragma unroll
  for (int e = 0; e < NEXP; ++e) {
    float v = acc[e];
    v += __shfl_xor(v, 32); v += __shfl_xor(v, 16); v += __shfl_xor(v, 8);
    v += __shfl_xor(v, 4);  v += __shfl_xor(v, 2);  v += __shfl_xor(v, 1);
    acc[e] = v;
  }
  if (lane == 0) {
    float p[NEXP];
    float mx = -1e30f;
#pragma unroll
    for (int e = 0; e < NEXP; ++e) { p[e] = acc[e] + bg[e]; mx = fmaxf(mx, p[e]); }
#pragma unroll
    for (int e = 0; e < NEXP; ++e) p[e] = expf(p[e] - mx);
    int i0 = 0;
#pragma unroll
    for (int e = 1; e < NEXP; ++e) if (p[e] > p[i0]) i0 = e;
    int i1 = (i0 == 0) ? 1 : 0;
#pragma unroll
    for (int e = 0; e < NEXP; ++e)
      if (e != i0 && e != i1 && p[e] > p[i1]) i1 = e;
    float wsum = p[i0] + p[i1];
    tok_e[t] = make_int2(i0, i1);
    tok_w[t] = make_float2(p[i0] / wsum, p[i1] / wsum);
  }
}

// ---------------------------------------------------------------- scatter (2 slot lists)
__global__ __launch_bounds__(256) void k_scatter(const int2* __restrict__ tok_e,
                                                 const float2* __restrict__ tok_w,
                                                 int* __restrict__ counts,
                                                 int* __restrict__ lt,
                                                 float* __restrict__ lw)
{
  __shared__ int lcnt[32];
  __shared__ int lbase[32];
  const int tid = threadIdx.x;
  if (tid < 32) lcnt[tid] = 0;
  __syncthreads();
  const int t = blockIdx.x * 256 + tid;
  int2 e = tok_e[t];
  float2 w = tok_w[t];
  int s0 = atomicAdd(&lcnt[e.x], 1);
  int s1 = atomicAdd(&lcnt[16 + e.y], 1);
  __syncthreads();
  if (tid < 32) lbase[tid] = atomicAdd(&counts[tid], lcnt[tid]);
  __syncthreads();
  int i0 = lbase[e.x] + s0;
  int i1 = lbase[16 + e.y] + s1;
  if (i0 < ECAP) { int p = e.x * ECAP + i0;            lt[p] = t; lw[p] = w.x; }
  if (i1 < ECAP) { int p = (10 + e.y) * ECAP + i1;     lt[p] = t; lw[p] = w.y; }
}

// ---------------------------------------------------------------- expert GEMM (MFMA)
// BM=64 BN=64 BK=32, 4 waves (2x2), wave tile 32x32. A f32 gathered + split in staging.
// MODE 0: H1[t*2+slot] = relu(o2[t] @ W1[e]^T + b1[e])         (K=512,N=256), z=slot*10+e
// MODE 1: D[t] = w*(H1[t*2] @ W2[e]^T + b2[e])        -> hl    (K=256,N=512), z=e (slot0)
// MODE 2: D[t] += w*(H1[t*2+1] @ W2[e]^T + b2[e])     RMW hl   (K=256,N=512), z=e (slot1)
template <int MODE>
__global__ __launch_bounds__(256) void k_mexpert(
    const float* __restrict__ Af32,
    const half_t* __restrict__ BhiAll, const half_t* __restrict__ BloAll,
    const float* __restrict__ biasAll,
    const int* __restrict__ counts, const int* __restrict__ lt,
    const float* __restrict__ lw,
    float* __restrict__ Hout, half_t* __restrict__ Dhi, half_t* __restrict__ Dlo,
    int K, int N)
{
  const int z = blockIdx.z;
  int slot, e;
  if (MODE == 0) { slot = z / 10; e = z - slot * 10; }
  else           { slot = MODE - 1; e = z; }
  const int cnt = counts[slot * 16 + e];
  const int i0 = blockIdx.x * 64;
  if (i0 >= cnt) return;
  const int col0 = blockIdx.y * 64;
  __shared__ half_t Ah[64][40], Al[64][40], Bh[64][40], Bl[64][40];
  __shared__ int rows[64];
  __shared__ float wts[64];
  const int tid = threadIdx.x;
  if (tid < 64) {
    int i = i0 + tid;
    rows[tid] = (i < cnt) ? lt[(slot * 10 + e) * ECAP + i] : -1;
    wts[tid]  = (i < cnt) ? lw[(slot * 10 + e) * ECAP + i] : 0.f;
  }
  __syncthreads();
  const half_t* Bhi = BhiAll + (size_t)e * K * N;
  const half_t* Blo = BloAll + (size_t)e * K * N;
  const int lane = tid & 63, wid = tid >> 6;
  const int wm = wid & 1, wn = wid >> 1;
  const int l16 = lane & 15, lq = lane >> 4;
  f4 acc1[2][2], acc2[2][2];
#pragma unroll
  for (int a = 0; a < 2; ++a)
#pragma unroll
    for (int b = 0; b < 2; ++b) {
      acc1[a][b] = {0.f, 0.f, 0.f, 0.f};
      acc2[a][b] = {0.f, 0.f, 0.f, 0.f};
    }
  const int sr = tid >> 2;
  const int sc = (tid & 3) << 3;
  for (int k0 = 0; k0 < K; k0 += 32) {
    {  // A gather + fp16 split
      int trow = rows[sr];
      float4 v0 = make_float4(0.f, 0.f, 0.f, 0.f), v1 = v0;
      if (trow >= 0) {
        size_t ar = (MODE == 0) ? (size_t)trow : (size_t)(trow * 2 + slot);
        const float* ap = Af32 + ar * K + k0 + sc;
        v0 = *(const float4*)ap;
        v1 = *(const float4*)(ap + 4);
      }
      h8 hh, ll;
      float vv[8] = {v0.x, v0.y, v0.z, v0.w, v1.x, v1.y, v1.z, v1.w};
#pragma unroll
      for (int i = 0; i < 8; ++i) { half_t a, b; split_hl(vv[i], a, b); hh[i] = a; ll[i] = b; }
      *(h8*)&Ah[sr][sc] = hh;
      *(h8*)&Al[sr][sc] = ll;
    }
    {  // B (W^T) staged
      const size_t gb = (size_t)(col0 + sr) * K + k0 + sc;
      *(uint4*)&Bh[sr][sc] = *(const uint4*)&Bhi[gb];
      *(uint4*)&Bl[sr][sc] = *(const uint4*)&Blo[gb];
    }
    __syncthreads();
    h8 ah[2], al2[2], bh[2], bl[2];
#pragma unroll
    for (int mt = 0; mt < 2; ++mt) {
      int r = wm * 32 + mt * 16 + l16;
      ah[mt]  = *(const h8*)&Ah[r][lq * 8];
      al2[mt] = *(const h8*)&Al[r][lq * 8];
    }
#pragma unroll
    for (int nt = 0; nt < 2; ++nt) {
      int r = wn * 32 + nt * 16 + l16;
      bh[nt] = *(const h8*)&Bh[r][lq * 8];
      bl[nt] = *(const h8*)&Bl[r][lq * 8];
    }
#pragma unroll
    for (int mt = 0; mt < 2; ++mt)
#pragma unroll
      for (int nt = 0; nt < 2; ++nt) {
        acc1[mt][nt] = __builtin_amdgcn_mfma_f32_16x16x32_f16(ah[mt], bh[nt], acc1[mt][nt], 0, 0, 0);
        acc2[mt][nt] = __builtin_amdgcn_mfma_f32_16x16x32_f16(ah[mt], bl[nt], acc2[mt][nt], 0, 0, 0);
        acc2[mt][nt] = __builtin_amdgcn_mfma_f32_16x16x32_f16(al2[mt], bh[nt], acc2[mt][nt], 0, 0, 0);
      }
    __syncthreads();
  }
#pragma unroll
  for (int mt = 0; mt < 2; ++mt) {
#pragma unroll
    for (int nt = 0; nt < 2; ++nt) {
      const int col = col0 + wn * 32 + nt * 16 + l16;
      const float bv = biasAll[(size_t)e * N + col];
#pragma unroll
      for (int r = 0; r < 4; ++r) {
        const int ridx = wm * 32 + mt * 16 + lq * 4 + r;
        const int trow = rows[ridx];
        if (trow < 0) continue;
        float v = acc1[mt][nt][r] + acc2[mt][nt][r] * LSCI;
        if (MODE == 0) {
          float o = fmaxf(v + bv, 0.f);
          Hout[(size_t)(trow * 2 + slot) * N + col] = o;
        } else {
          float o = wts[ridx] * (v + bv);
          const size_t di = (size_t)trow * N + col;
          if (MODE == 2) o += (float)Dhi[di] + (float)Dlo[di] * LSCI;
          half_t h, l; split_hl(o, h, l);
          Dhi[di] = h; Dlo[di] = l;
        }
      }
    }
  }
}

__global__ void k_zero(int* counts)
{
  if (threadIdx.x < 32) counts[threadIdx.x] = 0;
}

// ---------------------------------------------------------------- launcher
extern "C" void kernel_launch(void* const* d_in, const int* in_sizes, int n_in,
                              void* d_out, int out_size, void* d_ws, size_t ws_size,
                              hipStream_t stream)
{
  const float* x   = (const float*)d_in[0];
  const float* pos = (const float*)d_in[1];
  const float* Wp  = (const float*)d_in[2];
  const float* bp  = (const float*)d_in[3];
  const float* w1p[12];
  const float* w2p[12];
  for (int i = 0; i < 12; ++i) {
    w1p[i] = (const float*)d_in[4 + i];
    w2p[i] = (const float*)d_in[16 + i];
  }
  const float* Wv = (const float*)d_in[28];
  const float* bv = (const float*)d_in[29];
  const float* Wc = (const float*)d_in[30];
  const float* bc = (const float*)d_in[31];

  const size_t MiB = 1ull << 20;
  char* wsb = (char*)d_ws;

  // ---- weight region (0..33 MiB): hi/lo fp16 transposed weights
  half_t* wbase = (half_t*)wsb;
  size_t woff = 0;
  auto walloc = [&](size_t n) { half_t* p = wbase + woff; woff += n; return p; };
  half_t* wpT_hi = walloc(512 * 224);
  half_t* wpT_lo = walloc(512 * 224);
  struct LayerW {
    half_t *wip_h, *wip_l, *wqkv_h, *wqkv_l, *wo_h, *wo_l, *w1_h, *w1_l, *w2_h, *w2_l;
  } lw_[2];
  for (int L = 0; L < 2; ++L) {
    lw_[L].wip_h  = walloc(512 * 512);       lw_[L].wip_l  = walloc(512 * 512);
    lw_[L].wqkv_h = walloc(1536 * 512);      lw_[L].wqkv_l = walloc(1536 * 512);
    lw_[L].wo_h   = walloc(512 * 512);       lw_[L].wo_l   = walloc(512 * 512);
    lw_[L].w1_h   = walloc(10 * 256 * 512);  lw_[L].w1_l   = walloc(10 * 256 * 512);
    lw_[L].w2_h   = walloc(10 * 512 * 256);  lw_[L].w2_l   = walloc(10 * 512 * 256);
  }
  half_t* wvT_hi = walloc(512 * 512);
  half_t* wvT_lo = walloc(512 * 512);
  half_t* wcT_hi = walloc(512 * 512);
  half_t* wcT_lo = walloc(512 * 512);

  // ---- smalls (33..34 MiB)
  char* sm = wsb + 33 * MiB;
  int*    counts = (int*)sm;
  int*    lt     = (int*)(sm + 1024);
  float*  lwt    = (float*)(sm + 1024 + 327680);
  int2*   tok_e  = (int2*)(sm + 1024 + 655360);
  float2* tok_w  = (float2*)(sm + 1024 + 655360 + 131072);

  // ---- activation regions (ws confirmed 512 MiB by harness fill size)
  char* RA = wsb + 34 * MiB;    // tok_hl -> H1 f32 -> fv_hl
  char* RB = wsb + 66 * MiB;    // h_hl -> o2 f32
  char* RD = wsb + 98 * MiB;    // attn_hl -> dst_hl
  char* RQ = wsb + 130 * MiB;   // P_hl -> qkv f32 [16384][1536] (96 MiB)
  half_t* tokHi = (half_t*)RA;          half_t* tokLo = (half_t*)(RA + 16 * MiB);
  float*  H1    = (float*)RA;
  half_t* fvHi  = (half_t*)RA;          half_t* fvLo  = (half_t*)(RA + 16 * MiB);
  half_t* hHi   = (half_t*)RB;          half_t* hLo   = (half_t*)(RB + 16 * MiB);
  float*  o2    = (float*)RB;
  half_t* atHi  = (half_t*)RD;          half_t* atLo  = (half_t*)(RD + 16 * MiB);
  half_t* dstHi = (half_t*)RD;          half_t* dstLo = (half_t*)(RD + 16 * MiB);
  half_t* PHi   = (half_t*)RQ;          half_t* PLo   = (half_t*)(RQ + 8 * MiB);
  float*  qkvf  = (float*)RQ;

  float* out0 = (float*)d_out;
  float* out1 = out0 + 8388608;
  float* out2 = out0 + 16777216;
  float* out3 = out0 + 25165824;

  // ---- weight prep
  k_wprep<<<dim3(16, 7, 1),  dim3(256), 0, stream>>>(Wp, wpT_hi, wpT_lo, 196, 512, 224);
  for (int L = 0; L < 2; ++L) {
    const float* const* w = (L == 0) ? w1p : w2p;
    k_wprep<<<dim3(16, 16, 1),  dim3(256), 0, stream>>>(w[0], lw_[L].wip_h,  lw_[L].wip_l,  512, 512, 512);
    k_wprep<<<dim3(48, 16, 1),  dim3(256), 0, stream>>>(w[2], lw_[L].wqkv_h, lw_[L].wqkv_l, 512, 1536, 512);
    k_wprep<<<dim3(16, 16, 1),  dim3(256), 0, stream>>>(w[4], lw_[L].wo_h,   lw_[L].wo_l,   512, 512, 512);
    k_wprep<<<dim3(8, 16, 10),  dim3(256), 0, stream>>>(w[8], lw_[L].w1_h,   lw_[L].w1_l,   512, 256, 512);
    k_wprep<<<dim3(16, 8, 10),  dim3(256), 0, stream>>>(w[10], lw_[L].w2_h,  lw_[L].w2_l,   256, 512, 256);
  }
  k_wprep<<<dim3(16, 16, 1), dim3(256), 0, stream>>>(Wv, wvT_hi, wvT_lo, 512, 512, 512);
  k_wprep<<<dim3(16, 16, 1), dim3(256), 0, stream>>>(Wc, wcT_hi, wcT_lo, 512, 512, 512);

  // ---- patch embed
  k_patchify<<<dim3(14336), dim3(256), 0, stream>>>(x, PHi, PLo);
  k_mgemm<0><<<dim3(128, 4), dim3(256), 0, stream>>>(
      PHi, PLo, wpT_hi, wpT_lo, bp, pos, nullptr, tokHi, tokLo, 224, 512);

  auto moe = [&](int L, const half_t* inHi, const half_t* inLo) {
    const LayerW& W = lw_[L];
    const float* const* w = (L == 0) ? w1p : w2p;
    k_zero<<<dim3(1), dim3(64), 0, stream>>>(counts);
    k_mgemm<1><<<dim3(128, 4), dim3(256), 0, stream>>>(
        inHi, inLo, W.wip_h, W.wip_l, w[1], nullptr, nullptr, hHi, hLo, 512, 512);
    k_mgemm<2><<<dim3(128, 12), dim3(256), 0, stream>>>(
        hHi, hLo, W.wqkv_h, W.wqkv_l, w[3], nullptr, qkvf, nullptr, nullptr, 512, 1536);
    k_attn<<<dim3(256, 8), dim3(256), 0, stream>>>(qkvf, atHi, atLo);
    k_mgemm<2><<<dim3(128, 4), dim3(256), 0, stream>>>(
        atHi, atLo, W.wo_h, W.wo_l, w[5], nullptr, o2, nullptr, nullptr, 512, 512);
    k_gate<<<dim3(4096), dim3(256), 0, stream>>>(o2, w[6], w[7], tok_e, tok_w);
    k_scatter<<<dim3(64), dim3(256), 0, stream>>>(tok_e, tok_w, counts, lt, lwt);
    k_mexpert<0><<<dim3(64, 4, 20), dim3(256), 0, stream>>>(
        o2, W.w1_h, W.w1_l, w[9], counts, lt, lwt, H1, nullptr, nullptr, 512, 256);
    k_mexpert<1><<<dim3(64, 8, 10), dim3(256), 0, stream>>>(
        H1, W.w2_h, W.w2_l, w[11], counts, lt, lwt, nullptr, dstHi, dstLo, 256, 512);
    k_mexpert<2><<<dim3(64, 8, 10), dim3(256), 0, stream>>>(
        H1, W.w2_h, W.w2_l, w[11], counts, lt, lwt, nullptr, dstHi, dstLo, 256, 512);
  };

  // layer 1
  moe(0, tokHi, tokLo);
  k_mgemm<3><<<dim3(128, 4), dim3(256), 0, stream>>>(
      dstHi, dstLo, wvT_hi, wvT_lo, bv, nullptr, out0, fvHi, fvLo, 512, 512);
  k_mgemm<2><<<dim3(128, 4), dim3(256), 0, stream>>>(
      dstHi, dstLo, wcT_hi, wcT_lo, bc, nullptr, out2, nullptr, nullptr, 512, 512);
  // layer 2
  moe(1, fvHi, fvLo);
  k_mgemm<2><<<dim3(128, 4), dim3(256), 0, stream>>>(
      dstHi, dstLo, wvT_hi, wvT_lo, bv, nullptr, out1, nullptr, nullptr, 512, 512);
  k_mgemm<2><<<dim3(128, 4), dim3(256), 0, stream>>>(
      dstHi, dstLo, wcT_hi, wcT_lo, bc, nullptr, out3, nullptr, nullptr, 512, 512);
}

// Round 6
// 1316.450 us; speedup vs baseline: 1.1717x; 1.1717x over previous
//
#include <hip/hip_runtime.h>
#include <cstdint>
#include <cstddef>

typedef _Float16 half_t;
typedef _Float16 h8 __attribute__((ext_vector_type(8)));
typedef float f4 __attribute__((ext_vector_type(4)));

static constexpr int TOKENS = 16384;   // 64 images * 256 patches
static constexpr int DIM    = 512;
static constexpr int NEXP   = 10;
static constexpr int ECAP   = 4096;    // per (slot,expert) capacity
static constexpr float LSC  = 4096.f;  // lo-part scale (2^12)
static constexpr float LSCI = 1.f / 4096.f;

__device__ __forceinline__ void split_hl(float v, half_t& h, half_t& l) {
  h = (half_t)v;
  l = (half_t)((v - (float)h) * LSC);
}

// async global->LDS, 16B per lane; LDS dest = wave-uniform base + lane*16
__device__ __forceinline__ void gld16(const void* g, void* l) {
  __builtin_amdgcn_global_load_lds(
      (const __attribute__((address_space(1))) uint32_t*)g,
      (__attribute__((address_space(3))) uint32_t*)l, 16, 0, 0);
}

// ---------------------------------------------------------------- weight prep
// W [K][N] f32 -> W^T hi/lo f16 [N][KP], lo pre-scaled by 2^12
__global__ __launch_bounds__(256) void k_wprep(const float* __restrict__ W,
                                               half_t* __restrict__ Ohi,
                                               half_t* __restrict__ Olo,
                                               int K, int N, int KP)
{
  __shared__ float T[32][33];
  const int z = blockIdx.z;
  W   += (size_t)z * K * N;
  Ohi += (size_t)z * N * KP;
  Olo += (size_t)z * N * KP;
  const int t = threadIdx.x;
  const int bn = blockIdx.x * 32, bk = blockIdx.y * 32;
  {
    int nl = t & 31, kq = t >> 5;
#pragma unroll
    for (int i = 0; i < 4; ++i) {
      int kl = kq + i * 8;
      int k = bk + kl;
      T[kl][nl] = (k < K) ? W[(size_t)k * N + bn + nl] : 0.f;
    }
  }
  __syncthreads();
  {
    int kl = t & 31, nq = t >> 5;
#pragma unroll
    for (int i = 0; i < 4; ++i) {
      int nl = nq + i * 8;
      half_t h, l; split_hl(T[kl][nl], h, l);
      size_t o = (size_t)(bn + nl) * KP + bk + kl;
      Ohi[o] = h; Olo[o] = l;
    }
  }
}

// ---------------------------------------------------------------- patchify
__global__ __launch_bounds__(256) void k_patchify(const float* __restrict__ x,
                                                  half_t* __restrict__ Phi,
                                                  half_t* __restrict__ Plo)
{
  int gid = blockIdx.x * 256 + threadIdx.x;
  if (gid >= TOKENS * 224) return;
  int tk = gid / 224, p = gid - tk * 224;
  float v = 0.f;
  if (p < 196) {
    int b = tk >> 8, n = tk & 255;
    int ni = n >> 4, nj = n & 15;
    int pi = p / 14, pj = p - pi * 14;
    v = x[(size_t)b * 50176 + (size_t)(ni * 14 + pi) * 224 + (nj * 14 + pj)];
  }
  half_t h, l; split_hl(v, h, l);
  Phi[gid] = h; Plo[gid] = l;
}

// ---------------------------------------------------------------- MFMA GEMM
// C[M,N] = A[M,K] @ B^T[N,K] (+bias). fp16 hi/lo split, lo pre-scaled 2^12.
// BM=128 BN=64 BK=32, 4 waves (2m x 2n), wave tile 64x32.
// Staging: global_load_lds 16B into LINEAR LDS [rows][32] (m97 recipe).
// EPI: 0 +bias+pos->HL ; 1 +bias->HL ; 2 +bias->F32 ; 3 +bias->F32+HL
//      4 dual: col<512 -> Cf+HL, col>=512 -> Cf2   (bias|bias2)
//      5 dual: col<512 -> Cf,    col>=512 -> Cf2   (bias|bias2)
template <int EPI>
__global__ __launch_bounds__(256) void k_mgemm(
    const half_t* __restrict__ Ahi, const half_t* __restrict__ Alo,
    const half_t* __restrict__ Bhi, const half_t* __restrict__ Blo,
    const float* __restrict__ bias, const float* __restrict__ bias2,
    const float* __restrict__ pos,
    float* __restrict__ Cf, float* __restrict__ Cf2,
    half_t* __restrict__ Chi, half_t* __restrict__ Clo,
    int K, int Cld)
{
  __shared__ __align__(16) half_t AhL[128 * 32];
  __shared__ __align__(16) half_t AlL[128 * 32];
  __shared__ __align__(16) half_t BhL[64 * 32];
  __shared__ __align__(16) half_t BlL[64 * 32];
  const int tid = threadIdx.x;
  const int row0 = blockIdx.x * 128;
  const int col0 = blockIdx.y * 64;
  const int lane = tid & 63, wid = tid >> 6;
  const int wm = wid & 1, wn = wid >> 1;
  const int l16 = lane & 15, lq = lane >> 4;
  const int srA = lane >> 2;          // row within 16-row chunk
  const int scA = (lane & 3) << 3;    // half offset within row
  f4 acc1[4][2], acc2[4][2];
#pragma unroll
  for (int a = 0; a < 4; ++a)
#pragma unroll
    for (int b = 0; b < 2; ++b) {
      acc1[a][b] = {0.f, 0.f, 0.f, 0.f};
      acc2[a][b] = {0.f, 0.f, 0.f, 0.f};
    }
  for (int k0 = 0; k0 < K; k0 += 32) {
    // A: 8 chunks of 16 rows; wave w stages chunks 2w, 2w+1 (hi+lo)
#pragma unroll
    for (int c = 0; c < 2; ++c) {
      const int r0 = wid * 32 + c * 16;
      const size_t ga = (size_t)(row0 + r0 + srA) * K + k0 + scA;
      gld16(&Ahi[ga], &AhL[r0 * 32]);
      gld16(&Alo[ga], &AlL[r0 * 32]);
    }
    // B: 4 chunks of 16 rows; wave w stages chunk w (hi+lo)
    {
      const int r0 = wid * 16;
      const size_t gb = (size_t)(col0 + r0 + srA) * K + k0 + scA;
      gld16(&Bhi[gb], &BhL[r0 * 32]);
      gld16(&Blo[gb], &BlL[r0 * 32]);
    }
    __syncthreads();
    h8 ah[4], al2[4];
#pragma unroll
    for (int mt = 0; mt < 4; ++mt) {
      int r = wm * 64 + mt * 16 + l16;
      ah[mt]  = *(const h8*)&AhL[r * 32 + lq * 8];
      al2[mt] = *(const h8*)&AlL[r * 32 + lq * 8];
    }
#pragma unroll
    for (int nt = 0; nt < 2; ++nt) {
      int rb = wn * 32 + nt * 16 + l16;
      h8 bh = *(const h8*)&BhL[rb * 32 + lq * 8];
      h8 bl = *(const h8*)&BlL[rb * 32 + lq * 8];
#pragma unroll
      for (int mt = 0; mt < 4; ++mt) {
        acc1[mt][nt] = __builtin_amdgcn_mfma_f32_16x16x32_f16(ah[mt], bh, acc1[mt][nt], 0, 0, 0);
        acc2[mt][nt] = __builtin_amdgcn_mfma_f32_16x16x32_f16(ah[mt], bl, acc2[mt][nt], 0, 0, 0);
        acc2[mt][nt] = __builtin_amdgcn_mfma_f32_16x16x32_f16(al2[mt], bh, acc2[mt][nt], 0, 0, 0);
      }
    }
    __syncthreads();
  }
#pragma unroll
  for (int mt = 0; mt < 4; ++mt) {
#pragma unroll
    for (int nt = 0; nt < 2; ++nt) {
      const int col = col0 + wn * 32 + nt * 16 + l16;
      float bvv;
      if (EPI == 4 || EPI == 5) bvv = (col < 512) ? bias[col] : bias2[col - 512];
      else                      bvv = bias[col];
#pragma unroll
      for (int r = 0; r < 4; ++r) {
        const int row = row0 + wm * 64 + mt * 16 + lq * 4 + r;
        float v = acc1[mt][nt][r] + acc2[mt][nt][r] * LSCI + bvv;
        if (EPI == 0) v += pos[(size_t)(row & 255) * 512 + col];
        if (EPI == 4 || EPI == 5) {
          if (col < 512) {
            const size_t ci = (size_t)row * 512 + col;
            Cf[ci] = v;
            if (EPI == 4) { half_t h, l; split_hl(v, h, l); Chi[ci] = h; Clo[ci] = l; }
          } else {
            Cf2[(size_t)row * 512 + col - 512] = v;
          }
        } else {
          const size_t ci = (size_t)row * Cld + col;
          if (EPI == 2 || EPI == 3) Cf[ci] = v;
          if (EPI == 0 || EPI == 1 || EPI == 3) {
            half_t h, l; split_hl(v, h, l);
            Chi[ci] = h; Clo[ci] = l;
          }
        }
      }
    }
  }
}

// ---------------------------------------------------------------- attention (fp32)
__global__ __launch_bounds__(256) void k_attn(const float* __restrict__ qkv,
                                              half_t* __restrict__ oHi,
                                              half_t* __restrict__ oLo)
{
  __shared__ float Qs[64][68];
  __shared__ float Ks[64][68];
  __shared__ float Vs[64][68];
  const int n = blockIdx.x;
  const int h = blockIdx.y;
  const int tid = threadIdx.x;
  const int l = tid >> 2, q = tid & 3;
  {
    const float* rowp = qkv + (size_t)(l * 256 + n) * 1536 + h * 64;
#pragma unroll
    for (int i = 0; i < 4; ++i) {
      int c = q * 16 + i * 4;
      *(float4*)&Qs[l][c] = *(const float4*)(rowp + c);
      *(float4*)&Ks[l][c] = *(const float4*)(rowp + 512 + c);
      *(float4*)&Vs[l][c] = *(const float4*)(rowp + 1024 + c);
    }
  }
  __syncthreads();
  float s[16];
#pragma unroll
  for (int j = 0; j < 16; ++j) {
    int m = (j << 2) + q;
    float a = 0.f;
#pragma unroll
    for (int k4 = 0; k4 < 16; ++k4) {
      float4 qa = *(const float4*)&Qs[l][k4 * 4];
      float4 kb = *(const float4*)&Ks[m][k4 * 4];
      a = fmaf(qa.x, kb.x, a); a = fmaf(qa.y, kb.y, a);
      a = fmaf(qa.z, kb.z, a); a = fmaf(qa.w, kb.w, a);
    }
    s[j] = a * 0.125f;
  }
  float mx = s[0];
#pragma unroll
  for (int j = 1; j < 16; ++j) mx = fmaxf(mx, s[j]);
  mx = fmaxf(mx, __shfl_xor(mx, 1));
  mx = fmaxf(mx, __shfl_xor(mx, 2));
  float sum = 0.f;
#pragma unroll
  for (int j = 0; j < 16; ++j) { s[j] = expf(s[j] - mx); sum += s[j]; }
  sum += __shfl_xor(sum, 1);
  sum += __shfl_xor(sum, 2);
  float inv = 1.f / sum;
  __syncthreads();
#pragma unroll
  for (int j = 0; j < 16; ++j) Qs[l][(j << 2) + q] = s[j] * inv;
  __syncthreads();
  float av[16] = {};
  for (int m = 0; m < 64; ++m) {
    float p = Qs[l][m];
#pragma unroll
    for (int i = 0; i < 4; ++i) {
      float4 v4 = *(const float4*)&Vs[m][q * 16 + i * 4];
      av[i * 4 + 0] = fmaf(p, v4.x, av[i * 4 + 0]);
      av[i * 4 + 1] = fmaf(p, v4.y, av[i * 4 + 1]);
      av[i * 4 + 2] = fmaf(p, v4.z, av[i * 4 + 2]);
      av[i * 4 + 3] = fmaf(p, v4.w, av[i * 4 + 3]);
    }
  }
  const size_t base = (size_t)(l * 256 + n) * 512 + h * 64 + q * 16;
  h8 hv0, hv1, lv0, lv1;
#pragma unroll
  for (int i = 0; i < 8; ++i) { half_t hh, ll; split_hl(av[i], hh, ll); hv0[i] = hh; lv0[i] = ll; }
#pragma unroll
  for (int i = 0; i < 8; ++i) { half_t hh, ll; split_hl(av[8 + i], hh, ll); hv1[i] = hh; lv1[i] = ll; }
  *(h8*)&oHi[base] = hv0; *(h8*)&oHi[base + 8] = hv1;
  *(h8*)&oLo[base] = lv0; *(h8*)&oLo[base + 8] = lv1;
}

// ---------------------------------------------------------------- gating
__global__ __launch_bounds__(256) void k_gate(const float* __restrict__ o2,
                                              const float* __restrict__ Wg,
                                              const float* __restrict__ bg,
                                              int2* __restrict__ tok_e,
                                              float2* __restrict__ tok_w)
{
  const int wave = threadIdx.x >> 6;
  const int lane = threadIdx.x & 63;
  const int t = blockIdx.x * 4 + wave;
  const float* xr = o2 + (size_t)t * DIM;
  float acc[NEXP];
#pragma unroll
  for (int e = 0; e < NEXP; ++e) acc[e] = 0.f;
#pragma unroll
  for (int i = 0; i < 8; ++i) {
    int d = i * 64 + lane;
    float xv = xr[d];
    const float* wr = Wg + (size_t)d * NEXP;
#pragma unroll
    for (int e = 0; e < NEXP; ++e) acc[e] = fmaf(xv, wr[e], acc[e]);
  }
#pragma unroll
  for (int e = 0; e < NEXP; ++e) {
    float v = acc[e];
    v += __shfl_xor(v, 32); v += __shfl_xor(v, 16); v += __shfl_xor(v, 8);
    v += __shfl_xor(v, 4);  v += __shfl_xor(v, 2);  v += __shfl_xor(v, 1);
    acc[e] = v;
  }
  if (lane == 0) {
    float p[NEXP];
    float mx = -1e30f;
#pragma unroll
    for (int e = 0; e < NEXP; ++e) { p[e] = acc[e] + bg[e]; mx = fmaxf(mx, p[e]); }
#pragma unroll
    for (int e = 0; e < NEXP; ++e) p[e] = expf(p[e] - mx);
    int i0 = 0;
#pragma unroll
    for (int e = 1; e < NEXP; ++e) if (p[e] > p[i0]) i0 = e;
    int i1 = (i0 == 0) ? 1 : 0;
#pragma unroll
    for (int e = 0; e < NEXP; ++e)
      if (e != i0 && e != i1 && p[e] > p[i1]) i1 = e;
    float wsum = p[i0] + p[i1];
    tok_e[t] = make_int2(i0, i1);
    tok_w[t] = make_float2(p[i0] / wsum, p[i1] / wsum);
  }
}

// ---------------------------------------------------------------- scatter
__global__ __launch_bounds__(256) void k_scatter(const int2* __restrict__ tok_e,
                                                 const float2* __restrict__ tok_w,
                                                 int* __restrict__ counts,
                                                 int* __restrict__ lt,
                                                 float* __restrict__ lw)
{
  __shared__ int lcnt[32];
  __shared__ int lbase[32];
  const int tid = threadIdx.x;
  if (tid < 32) lcnt[tid] = 0;
  __syncthreads();
  const int t = blockIdx.x * 256 + tid;
  int2 e = tok_e[t];
  float2 w = tok_w[t];
  int s0 = atomicAdd(&lcnt[e.x], 1);
  int s1 = atomicAdd(&lcnt[16 + e.y], 1);
  __syncthreads();
  if (tid < 32) lbase[tid] = atomicAdd(&counts[tid], lcnt[tid]);
  __syncthreads();
  int i0 = lbase[e.x] + s0;
  int i1 = lbase[16 + e.y] + s1;
  if (i0 < ECAP) { int p = e.x * ECAP + i0;            lt[p] = t; lw[p] = w.x; }
  if (i1 < ECAP) { int p = (10 + e.y) * ECAP + i1;     lt[p] = t; lw[p] = w.y; }
}

// ---------------------------------------------------------------- expert GEMM (MFMA)
// BM=64 BN=64 BK=32, 4 waves (2x2), wave tile 32x32.
// A: gathered f32 rows -> split -> padded LDS (ds_write).  B: global_load_lds linear.
// MODE 0: H1[t*2+slot] = relu(o2[t] @ W1[e]^T + b1[e])      (K=512,N=256), z=slot*10+e
// MODE 1: D[t]  = w*(H1[t*2]   @ W2[e]^T + b2[e]) -> hl     (K=256,N=512), z=e
// MODE 2: D[t] += w*(H1[t*2+1] @ W2[e]^T + b2[e]) RMW hl    (K=256,N=512), z=e
template <int MODE>
__global__ __launch_bounds__(256) void k_mexpert(
    const float* __restrict__ Af32,
    const half_t* __restrict__ BhiAll, const half_t* __restrict__ BloAll,
    const float* __restrict__ biasAll,
    const int* __restrict__ counts, const int* __restrict__ lt,
    const float* __restrict__ lw,
    float* __restrict__ Hout, half_t* __restrict__ Dhi, half_t* __restrict__ Dlo,
    int K, int N)
{
  const int z = blockIdx.z;
  int slot, e;
  if (MODE == 0) { slot = z / 10; e = z - slot * 10; }
  else           { slot = MODE - 1; e = z; }
  const int cnt = counts[slot * 16 + e];
  const int i0 = blockIdx.x * 64;
  if (i0 >= cnt) return;
  const int col0 = blockIdx.y * 64;
  __shared__ __align__(16) half_t Ah[64][40], Al[64][40];
  __shared__ __align__(16) half_t BhL[64 * 32], BlL[64 * 32];
  __shared__ int rows[64];
  __shared__ float wts[64];
  const int tid = threadIdx.x;
  if (tid < 64) {
    int i = i0 + tid;
    rows[tid] = (i < cnt) ? lt[(slot * 10 + e) * ECAP + i] : -1;
    wts[tid]  = (i < cnt) ? lw[(slot * 10 + e) * ECAP + i] : 0.f;
  }
  __syncthreads();
  const half_t* Bhi = BhiAll + (size_t)e * K * N;
  const half_t* Blo = BloAll + (size_t)e * K * N;
  const int lane = tid & 63, wid = tid >> 6;
  const int wm = wid & 1, wn = wid >> 1;
  const int l16 = lane & 15, lq = lane >> 4;
  const int srA = lane >> 2;
  const int scA = (lane & 3) << 3;
  f4 acc1[2][2], acc2[2][2];
#pragma unroll
  for (int a = 0; a < 2; ++a)
#pragma unroll
    for (int b = 0; b < 2; ++b) {
      acc1[a][b] = {0.f, 0.f, 0.f, 0.f};
      acc2[a][b] = {0.f, 0.f, 0.f, 0.f};
    }
  const int sr = tid >> 2;
  const int sc = (tid & 3) << 3;
  for (int k0 = 0; k0 < K; k0 += 32) {
    {  // B via async DMA (linear LDS)
      const int r0 = wid * 16;
      const size_t gb = (size_t)(col0 + r0 + srA) * K + k0 + scA;
      gld16(&Bhi[gb], &BhL[r0 * 32]);
      gld16(&Blo[gb], &BlL[r0 * 32]);
    }
    {  // A gather + fp16 split (reg-staged)
      int trow = rows[sr];
      float4 v0 = make_float4(0.f, 0.f, 0.f, 0.f), v1 = v0;
      if (trow >= 0) {
        size_t ar = (MODE == 0) ? (size_t)trow : (size_t)(trow * 2 + slot);
        const float* ap = Af32 + ar * K + k0 + sc;
        v0 = *(const float4*)ap;
        v1 = *(const float4*)(ap + 4);
      }
      h8 hh, ll;
      float vv[8] = {v0.x, v0.y, v0.z, v0.w, v1.x, v1.y, v1.z, v1.w};
#pragma unroll
      for (int i = 0; i < 8; ++i) { half_t a, b; split_hl(vv[i], a, b); hh[i] = a; ll[i] = b; }
      *(h8*)&Ah[sr][sc] = hh;
      *(h8*)&Al[sr][sc] = ll;
    }
    __syncthreads();
    h8 ah[2], al2[2], bh[2], bl[2];
#pragma unroll
    for (int mt = 0; mt < 2; ++mt) {
      int r = wm * 32 + mt * 16 + l16;
      ah[mt]  = *(const h8*)&Ah[r][lq * 8];
      al2[mt] = *(const h8*)&Al[r][lq * 8];
    }
#pragma unroll
    for (int nt = 0; nt < 2; ++nt) {
      int r = wn * 32 + nt * 16 + l16;
      bh[nt] = *(const h8*)&BhL[r * 32 + lq * 8];
      bl[nt] = *(const h8*)&BlL[r * 32 + lq * 8];
    }
#pragma unroll
    for (int mt = 0; mt < 2; ++mt)
#pragma unroll
      for (int nt = 0; nt < 2; ++nt) {
        acc1[mt][nt] = __builtin_amdgcn_mfma_f32_16x16x32_f16(ah[mt], bh[nt], acc1[mt][nt], 0, 0, 0);
        acc2[mt][nt] = __builtin_amdgcn_mfma_f32_16x16x32_f16(ah[mt], bl[nt], acc2[mt][nt], 0, 0, 0);
        acc2[mt][nt] = __builtin_amdgcn_mfma_f32_16x16x32_f16(al2[mt], bh[nt], acc2[mt][nt], 0, 0, 0);
      }
    __syncthreads();
  }
#pragma unroll
  for (int mt = 0; mt < 2; ++mt) {
#pragma unroll
    for (int nt = 0; nt < 2; ++nt) {
      const int col = col0 + wn * 32 + nt * 16 + l16;
      const float bv = biasAll[(size_t)e * N + col];
#pragma unroll
      for (int r = 0; r < 4; ++r) {
        const int ridx = wm * 32 + mt * 16 + lq * 4 + r;
        const int trow = rows[ridx];
        if (trow < 0) continue;
        float v = acc1[mt][nt][r] + acc2[mt][nt][r] * LSCI;
        if (MODE == 0) {
          float o = fmaxf(v + bv, 0.f);
          Hout[(size_t)(trow * 2 + slot) * N + col] = o;
        } else {
          float o = wts[ridx] * (v + bv);
          const size_t di = (size_t)trow * N + col;
          if (MODE == 2) o += (float)Dhi[di] + (float)Dlo[di] * LSCI;
          half_t h, l; split_hl(o, h, l);
          Dhi[di] = h; Dlo[di] = l;
        }
      }
    }
  }
}

__global__ void k_zero(int* counts)
{
  if (threadIdx.x < 32) counts[threadIdx.x] = 0;
}

// ---------------------------------------------------------------- launcher
extern "C" void kernel_launch(void* const* d_in, const int* in_sizes, int n_in,
                              void* d_out, int out_size, void* d_ws, size_t ws_size,
                              hipStream_t stream)
{
  const float* x   = (const float*)d_in[0];
  const float* pos = (const float*)d_in[1];
  const float* Wp  = (const float*)d_in[2];
  const float* bp  = (const float*)d_in[3];
  const float* w1p[12];
  const float* w2p[12];
  for (int i = 0; i < 12; ++i) {
    w1p[i] = (const float*)d_in[4 + i];
    w2p[i] = (const float*)d_in[16 + i];
  }
  const float* Wv = (const float*)d_in[28];
  const float* bv = (const float*)d_in[29];
  const float* Wc = (const float*)d_in[30];
  const float* bc = (const float*)d_in[31];

  const size_t MiB = 1ull << 20;
  char* wsb = (char*)d_ws;

  // ---- weight region (0..33 MiB): hi/lo fp16 transposed weights
  half_t* wbase = (half_t*)wsb;
  size_t woff = 0;
  auto walloc = [&](size_t n) { half_t* p = wbase + woff; woff += n; return p; };
  half_t* wpT_hi = walloc(512 * 224);
  half_t* wpT_lo = walloc(512 * 224);
  struct LayerW {
    half_t *wip_h, *wip_l, *wqkv_h, *wqkv_l, *wo_h, *wo_l, *w1_h, *w1_l, *w2_h, *w2_l;
  } lw_[2];
  for (int L = 0; L < 2; ++L) {
    lw_[L].wip_h  = walloc(512 * 512);       lw_[L].wip_l  = walloc(512 * 512);
    lw_[L].wqkv_h = walloc(1536 * 512);      lw_[L].wqkv_l = walloc(1536 * 512);
    lw_[L].wo_h   = walloc(512 * 512);       lw_[L].wo_l   = walloc(512 * 512);
    lw_[L].w1_h   = walloc(10 * 256 * 512);  lw_[L].w1_l   = walloc(10 * 256 * 512);
    lw_[L].w2_h   = walloc(10 * 512 * 256);  lw_[L].w2_l   = walloc(10 * 512 * 256);
  }
  half_t* wvcT_hi = walloc(1024 * 512);   // rows 0-511 Wv^T, 512-1023 Wc^T
  half_t* wvcT_lo = walloc(1024 * 512);

  // ---- smalls (33..34 MiB)
  char* sm = wsb + 33 * MiB;
  int*    counts = (int*)sm;
  int*    lt     = (int*)(sm + 1024);
  float*  lwt    = (float*)(sm + 1024 + 327680);
  int2*   tok_e  = (int2*)(sm + 1024 + 655360);
  float2* tok_w  = (float2*)(sm + 1024 + 655360 + 131072);

  // ---- activation regions
  char* RA = wsb + 34 * MiB;    // tok_hl -> H1 f32 -> fv_hl
  char* RB = wsb + 66 * MiB;    // h_hl -> o2 f32
  char* RD = wsb + 98 * MiB;    // attn_hl -> dst_hl
  char* RQ = wsb + 130 * MiB;   // P_hl -> qkv f32 (96 MiB)
  half_t* tokHi = (half_t*)RA;          half_t* tokLo = (half_t*)(RA + 16 * MiB);
  float*  H1    = (float*)RA;
  half_t* fvHi  = (half_t*)RA;          half_t* fvLo  = (half_t*)(RA + 16 * MiB);
  half_t* hHi   = (half_t*)RB;          half_t* hLo   = (half_t*)(RB + 16 * MiB);
  float*  o2    = (float*)RB;
  half_t* atHi  = (half_t*)RD;          half_t* atLo  = (half_t*)(RD + 16 * MiB);
  half_t* dstHi = (half_t*)RD;          half_t* dstLo = (half_t*)(RD + 16 * MiB);
  half_t* PHi   = (half_t*)RQ;          half_t* PLo   = (half_t*)(RQ + 8 * MiB);
  float*  qkvf  = (float*)RQ;

  float* out0 = (float*)d_out;
  float* out1 = out0 + 8388608;
  float* out2 = out0 + 16777216;
  float* out3 = out0 + 25165824;

  // ---- weight prep
  k_wprep<<<dim3(16, 7, 1),  dim3(256), 0, stream>>>(Wp, wpT_hi, wpT_lo, 196, 512, 224);
  for (int L = 0; L < 2; ++L) {
    const float* const* w = (L == 0) ? w1p : w2p;
    k_wprep<<<dim3(16, 16, 1),  dim3(256), 0, stream>>>(w[0], lw_[L].wip_h,  lw_[L].wip_l,  512, 512, 512);
    k_wprep<<<dim3(48, 16, 1),  dim3(256), 0, stream>>>(w[2], lw_[L].wqkv_h, lw_[L].wqkv_l, 512, 1536, 512);
    k_wprep<<<dim3(16, 16, 1),  dim3(256), 0, stream>>>(w[4], lw_[L].wo_h,   lw_[L].wo_l,   512, 512, 512);
    k_wprep<<<dim3(8, 16, 10),  dim3(256), 0, stream>>>(w[8], lw_[L].w1_h,   lw_[L].w1_l,   512, 256, 512);
    k_wprep<<<dim3(16, 8, 10),  dim3(256), 0, stream>>>(w[10], lw_[L].w2_h,  lw_[L].w2_l,   256, 512, 256);
  }
  k_wprep<<<dim3(16, 16, 1), dim3(256), 0, stream>>>(Wv, wvcT_hi, wvcT_lo, 512, 512, 512);
  k_wprep<<<dim3(16, 16, 1), dim3(256), 0, stream>>>(Wc, wvcT_hi + 512 * 512,
                                                     wvcT_lo + 512 * 512, 512, 512, 512);

  // ---- patch embed
  k_patchify<<<dim3(14336), dim3(256), 0, stream>>>(x, PHi, PLo);
  k_mgemm<0><<<dim3(128, 8), dim3(256), 0, stream>>>(
      PHi, PLo, wpT_hi, wpT_lo, bp, nullptr, pos, nullptr, nullptr, tokHi, tokLo, 224, 512);

  auto moe = [&](int L, const half_t* inHi, const half_t* inLo) {
    const LayerW& W = lw_[L];
    const float* const* w = (L == 0) ? w1p : w2p;
    k_zero<<<dim3(1), dim3(64), 0, stream>>>(counts);
    k_mgemm<1><<<dim3(128, 8), dim3(256), 0, stream>>>(
        inHi, inLo, W.wip_h, W.wip_l, w[1], nullptr, nullptr, nullptr, nullptr,
        hHi, hLo, 512, 512);
    k_mgemm<2><<<dim3(128, 24), dim3(256), 0, stream>>>(
        hHi, hLo, W.wqkv_h, W.wqkv_l, w[3], nullptr, nullptr, qkvf, nullptr,
        nullptr, nullptr, 512, 1536);
    k_attn<<<dim3(256, 8), dim3(256), 0, stream>>>(qkvf, atHi, atLo);
    k_mgemm<2><<<dim3(128, 8), dim3(256), 0, stream>>>(
        atHi, atLo, W.wo_h, W.wo_l, w[5], nullptr, nullptr, o2, nullptr,
        nullptr, nullptr, 512, 512);
    k_gate<<<dim3(4096), dim3(256), 0, stream>>>(o2, w[6], w[7], tok_e, tok_w);
    k_scatter<<<dim3(64), dim3(256), 0, stream>>>(tok_e, tok_w, counts, lt, lwt);
    k_mexpert<0><<<dim3(64, 4, 20), dim3(256), 0, stream>>>(
        o2, W.w1_h, W.w1_l, w[9], counts, lt, lwt, H1, nullptr, nullptr, 512, 256);
    k_mexpert<1><<<dim3(64, 8, 10), dim3(256), 0, stream>>>(
        H1, W.w2_h, W.w2_l, w[11], counts, lt, lwt, nullptr, dstHi, dstLo, 256, 512);
    k_mexpert<2><<<dim3(64, 8, 10), dim3(256), 0, stream>>>(
        H1, W.w2_h, W.w2_l, w[11], counts, lt, lwt, nullptr, dstHi, dstLo, 256, 512);
  };

  // layer 1  (dual-output: out0=first_vec + fv_hl, out2=cls_first)
  moe(0, tokHi, tokLo);
  k_mgemm<4><<<dim3(128, 16), dim3(256), 0, stream>>>(
      dstHi, dstLo, wvcT_hi, wvcT_lo, bv, bc, nullptr, out0, out2, fvHi, fvLo, 512, 512);
  // layer 2  (dual-output: out1=second_vec, out3=cls_second)
  moe(1, fvHi, fvLo);
  k_mgemm<5><<<dim3(128, 16), dim3(256), 0, stream>>>(
      dstHi, dstLo, wvcT_hi, wvcT_lo, bv, bc, nullptr, out1, out3, nullptr, nullptr, 512, 512);
}